// Round 10
// baseline (337.512 us; speedup 1.0000x reference)
//
#include <hip/hip_runtime.h>

#define N_NODES 262144

typedef short s16x8 __attribute__((ext_vector_type(8)));
typedef float f32x4 __attribute__((ext_vector_type(4)));

// 2 f32 -> packed bf16x2 in one VOP3.
static __device__ __forceinline__ unsigned cvtpk(float lo, float hi) {
  unsigned r;
  asm("v_cvt_pk_bf16_f32 %0, %1, %2" : "=v"(r) : "v"(lo), "v"(hi));
  return r;
}

static __device__ __forceinline__ unsigned short f2bf(float f) {
  union { float f; unsigned u; } v; v.f = f;
  unsigned u = v.u;
  u += 0x7FFFu + ((u >> 16) & 1u);   // round-to-nearest-even
  return (unsigned short)(u >> 16);
}

static __device__ __forceinline__ unsigned long long pack4bf(f32x4 v) {
  unsigned u0 = (unsigned)f2bf(v.x) | ((unsigned)f2bf(v.y) << 16);
  unsigned u1 = (unsigned)f2bf(v.z) | ((unsigned)f2bf(v.w) << 16);
  return (unsigned long long)u0 | ((unsigned long long)u1 << 32);
}

static __device__ __forceinline__ float fsig(float x) {
  return __builtin_amdgcn_rcpf(1.0f + __expf(-x));
}
static __device__ __forceinline__ float ftanh(float x) {
  return 2.0f * __builtin_amdgcn_rcpf(1.0f + __expf(-2.0f * x)) - 1.0f;
}

// async global->LDS DMA, 16B/lane: per-lane global src, wave-uniform LDS base (m104)
static __device__ __forceinline__ void gload_lds16(const float* g, char* l) {
  __builtin_amdgcn_global_load_lds(
      (const __attribute__((address_space(1))) unsigned*)g,
      (__attribute__((address_space(3))) unsigned*)l, 16, 0, 0);
}

// Weight prep:
//  Wh2[kb][n][ki] (16 x 64 x 32 bf16)  = W_hid[n][kb*32+ki]
//  W2 [kb][n][ki] ( 8 x 512 x 32 bf16) = k<128 ? W_ih[n][k] : W_hh[n][k-128]
//  biasg[512] = b_ih + b_hh
__global__ void prep_kernel(const float* __restrict__ Whid, const float* __restrict__ Wih,
                            const float* __restrict__ Whh, const float* __restrict__ bih,
                            const float* __restrict__ bhh,
                            unsigned short* __restrict__ oWh2, unsigned short* __restrict__ oW2,
                            float* __restrict__ oBias) {
  int t = blockIdx.x * 256 + threadIdx.x;
  if (t < 32768) {
    int kb = t >> 11, n = (t >> 5) & 63, ki = t & 31;
    oWh2[t] = f2bf(Whid[n * 512 + kb * 32 + ki]);
  }
  if (t < 131072) {
    int kb = t >> 14, n = (t >> 5) & 511, ki = t & 31;
    int k = kb * 32 + ki;
    float v = (k < 128) ? Wih[n * 128 + k] : Whh[n * 128 + (k - 128)];
    oW2[t] = f2bf(v);
  }
  if (t < 512) oBias[t] = bih[t] + bhh[t];
}

// ------------------- Kernel A: a_v = relu([hvv|Hv] @ Wh^T + bhid) -------------------
// 256 threads, BM=64, K chunked at 32 through 2x8KB DMA'd LDS buffers.
// Chunk layout: [64 rows][32 f32] (128B rows), 32B slots XOR-swizzled by row&3
// on the DMA *source* and re-applied at fragment read (G4 / m173).
__global__ __launch_bounds__(256, 8) void node_av_kernel(
    const float* __restrict__ Hv, const float* __restrict__ hvv,
    const unsigned short* __restrict__ Wh2, const float* __restrict__ bhid,
    unsigned short* __restrict__ av_out)
{
  __shared__ __align__(16) char lds[16384];   // 2 x 8KB chunk buffers
  const int tid = threadIdx.x;
  const int w   = tid >> 6;     // wave 0..3
  const int l   = tid & 63;
  const int l15 = l & 15;
  const int lk  = l >> 4;
  const int node0 = blockIdx.x * 64;
  const char* WhB = (const char*)Wh2;

  // per-lane DMA source geometry (2 calls/thread/chunk: i=0,1; wave covers 2KB)
  // lin = w*2048 + i*1024 + l*16 ; r = lin>>7 ; c16 = (lin>>4)&7
  // global 16B chunk = ((c16>>1) ^ (r&3))*2 + (c16&1)

#define ISSUE_CHUNK(c, buf)                                                       \
  {                                                                               \
    const float* srcb = ((c) < 8) ? hvv : Hv;                                     \
    const int kcol = ((c) & 7) * 32;                                              \
    _Pragma("unroll")                                                             \
    for (int i = 0; i < 2; ++i) {                                                 \
      int off = w * 2048 + i * 1024;                                              \
      int lin = off + l * 16;                                                     \
      int r   = lin >> 7;                                                         \
      int c16 = (lin >> 4) & 7;                                                   \
      int g16 = ((((c16 >> 1) ^ (r & 3)) << 1) | (c16 & 1));                      \
      gload_lds16(srcb + (size_t)(node0 + r) * 256 + kcol + g16 * 4, (buf) + off);\
    }                                                                             \
  }

  f32x4 acc[4] = {f32x4{0.f,0.f,0.f,0.f}, f32x4{0.f,0.f,0.f,0.f},
                  f32x4{0.f,0.f,0.f,0.f}, f32x4{0.f,0.f,0.f,0.f}};

  ISSUE_CHUNK(0, lds);
  __syncthreads();   // chunk 0 staged (vmcnt drain)

#pragma unroll
  for (int c = 0; c < 16; ++c) {
    char* cur = lds + ((c & 1) << 13);
    if (c < 15) ISSUE_CHUNK(c + 1, lds + (((c + 1) & 1) << 13));

    // A-frag: row w*16+l15, k = lk*8..+8 (f32 -> bf16 via cvt_pk)
    int r = (w << 4) + l15;
    const char* ap = cur + r * 128 + ((lk ^ (r & 3)) << 5);
    f32x4 A0 = *(const f32x4*)ap;
    f32x4 A1 = *(const f32x4*)(ap + 16);
    union { unsigned u[4]; s16x8 v; } t;
    t.u[0] = cvtpk(A0.x, A0.y); t.u[1] = cvtpk(A0.z, A0.w);
    t.u[2] = cvtpk(A1.x, A1.y); t.u[3] = cvtpk(A1.z, A1.w);
#pragma unroll
    for (int nt = 0; nt < 4; ++nt) {
      s16x8 bf = *(const s16x8*)(WhB + c * 4096 + (nt * 16 + l15) * 64 + lk * 16);
      acc[nt] = __builtin_amdgcn_mfma_f32_16x16x32_bf16(t.v, bf, acc[nt], 0, 0, 0);
    }
    __syncthreads();   // chunk c+1 staged AND chunk c reads done
  }

  // epilogue: relu(acc + bias) -> bf16 a_v
#pragma unroll
  for (int nt = 0; nt < 4; ++nt) {
    int col = nt * 16 + l15;
    float bb = bhid[col];
#pragma unroll
    for (int rg = 0; rg < 4; ++rg) {
      int row = (w << 4) + (lk << 2) + rg;
      av_out[(size_t)(node0 + row) * 64 + col] = f2bf(fmaxf(acc[nt][rg] + bb, 0.f));
    }
  }
#undef ISSUE_CHUNK
}

// ------------------- Kernel B: A2 assembly + gate GEMM + LSTM pointwise -------------------
// A2: 64 rows x 256 bf16 (512B rows) = [e_v(64) | a_v(64) | hv(128)], XOR-swizzled.
#define SWZ2(m, b) ((((m) * 512) + (b)) ^ (((m) & 7) << 4))

__global__ __launch_bounds__(512, 4) void node_gate_kernel(
    const float* __restrict__ xv, const float* __restrict__ hvp,
    const float* __restrict__ cvp, const int* __restrict__ tsm,
    const float* __restrict__ Wpos, const float* __restrict__ bpos,
    const unsigned short* __restrict__ av,
    const unsigned short* __restrict__ W2,
    const float* __restrict__ biasg,
    float* __restrict__ hvo, float* __restrict__ cvo)
{
  __shared__ __align__(16) char lds[32768];

  const int tid = threadIdx.x;
  const int w   = tid >> 6;      // wave 0..7
  const int l   = tid & 63;
  const int l15 = l & 15;
  const int lk  = l >> 4;
  const int node0 = blockIdx.x * 64;
  const int d   = 16 * w + l15;  // gate-dim slice

  // ---- a_v -> A2 cols [64,128): one b128 per thread, coalesced
  {
    int m = tid >> 3, c8 = tid & 7;
    s16x8 va = *(const s16x8*)(av + (size_t)(node0 + m) * 64 + c8 * 8);
    *(s16x8*)(lds + SWZ2(m, 128 + c8 * 16)) = va;
  }

  unsigned long long actmask = __ballot(tsm[node0 + l] == 1);  // bit m = row m active

  // ---- e_v -> A2 cols [0,64)
#pragma unroll
  for (int it = 0; it < 4; ++it) {
    int p = tid + it * 512;                 // 64 rows x 32 pairs
    int m = p >> 5, jp = p & 31;
    float x0 = xv[(size_t)(node0 + m) * 2 + 0];
    float x1 = xv[(size_t)(node0 + m) * 2 + 1];
    float e0 = fmaxf(x0 * Wpos[(2*jp  )*2] + x1 * Wpos[(2*jp  )*2+1] + bpos[2*jp  ], 0.f);
    float e1 = fmaxf(x0 * Wpos[(2*jp+1)*2] + x1 * Wpos[(2*jp+1)*2+1] + bpos[2*jp+1], 0.f);
    unsigned u = cvtpk(e0, e1);
    *(unsigned*)(lds + SWZ2(m, jp * 4)) = u;
  }
  // ---- hv -> A2 cols [128,256)
#pragma unroll
  for (int it = 0; it < 4; ++it) {
    int p = tid + it * 512;                 // 64 rows x 32 f32x4-chunks
    int m = p >> 5, c4 = p & 31;
    f32x4 v = *(const f32x4*)(hvp + (size_t)(node0 + m) * 128 + c4 * 4);
    *(unsigned long long*)(lds + SWZ2(m, 256 + c4 * 8)) = pack4bf(v);
  }

  __syncthreads();   // A2 complete (single barrier in this kernel)

  float bs[4];
#pragma unroll
  for (int j = 0; j < 4; ++j) bs[j] = biasg[128 * j + d];

  // ---- gate GEMM: A2(64x256) @ [Wih;Whh]^T; wave w owns d-slice [16w,16w+16) of all 4 gates
  f32x4 acc2[4][4];
#pragma unroll
  for (int mi = 0; mi < 4; ++mi)
#pragma unroll
    for (int j = 0; j < 4; ++j) acc2[mi][j] = f32x4{0.f,0.f,0.f,0.f};

#pragma unroll
  for (int kk = 0; kk < 8; ++kk) {
    s16x8 a[4];
#pragma unroll
    for (int mi = 0; mi < 4; ++mi)
      a[mi] = *(const s16x8*)(lds + SWZ2(mi * 16 + l15, kk * 64 + lk * 16));
    const char* wb = (const char*)W2 + kk * 32768 + lk * 16;
#pragma unroll
    for (int j = 0; j < 4; ++j) {
      s16x8 bf = *(const s16x8*)(wb + (size_t)(16 * w + 128 * j + l15) * 64);
#pragma unroll
      for (int mi = 0; mi < 4; ++mi)
        acc2[mi][j] = __builtin_amdgcn_mfma_f32_16x16x32_bf16(a[mi], bf, acc2[mi][j], 0, 0, 0);
    }
  }

  // ---- LSTM pointwise + mask select
#pragma unroll
  for (int mi = 0; mi < 4; ++mi) {
#pragma unroll
    for (int r = 0; r < 4; ++r) {
      int m = mi * 16 + lk * 4 + r;
      size_t node = (size_t)node0 + m;
      int act = (int)((actmask >> m) & 1ull);
      float gi = acc2[mi][0][r] + bs[0];
      float gf = acc2[mi][1][r] + bs[1];
      float gg = acc2[mi][2][r] + bs[2];
      float go = acc2[mi][3][r] + bs[3];
      float i_ = fsig(gi), f_ = fsig(gf), o_ = fsig(go);
      float g_ = ftanh(gg);
      float co = cvp[node * 128 + d];
      float ho = hvp[node * 128 + d];
      float cn = f_ * co + i_ * g_;
      float hn = o_ * ftanh(cn);
      hvo[node * 128 + d] = act ? hn : ho;
      cvo[node * 128 + d] = act ? cn : co;
    }
  }
}

// ------------------- Fallback: round-2 fused kernel (proven 284 us) -------------------
#define SWZA(m, b) ((((m) * 1024) + (b)) ^ (((m) & 7) << 4))

__global__ __launch_bounds__(512, 4) void node_rnn_fused(
    const float* __restrict__ Hv, const float* __restrict__ hvv,
    const float* __restrict__ xv, const float* __restrict__ hvp,
    const float* __restrict__ cvp, const int* __restrict__ tsm,
    const float* __restrict__ Wpos, const float* __restrict__ bpos,
    const float* __restrict__ bhid,
    const unsigned short* __restrict__ Wh2,
    const unsigned short* __restrict__ W2,
    const float* __restrict__ biasg,
    float* __restrict__ hvo, float* __restrict__ cvo)
{
  __shared__ __align__(16) char lds[65536];
  const int tid = threadIdx.x;
  const int w   = tid >> 6;
  const int l   = tid & 63;
  const int l15 = l & 15;
  const int lk  = l >> 4;
  const int wr  = w >> 2;
  const int wc  = w & 3;
  const int node0 = blockIdx.x * 64;

#pragma unroll
  for (int it = 0; it < 16; ++it) {
    int p = tid + it * 512;
    int m = p >> 7, ch = p & 127;
    const float* src = (ch < 64) ? (hvv + (size_t)(node0 + m) * 256 + ch * 4)
                                 : (Hv  + (size_t)(node0 + m) * 256 + (ch - 64) * 4);
    f32x4 v = *(const f32x4*)src;
    *(unsigned long long*)(lds + SWZA(m, ch * 8)) = pack4bf(v);
  }
  float ev[8];
#pragma unroll
  for (int it = 0; it < 8; ++it) {
    int p = tid + it * 512;
    int m = p >> 6, j = p & 63;
    float x0 = xv[(size_t)(node0 + m) * 2 + 0];
    float x1 = xv[(size_t)(node0 + m) * 2 + 1];
    ev[it] = fmaxf(x0 * Wpos[j * 2 + 0] + x1 * Wpos[j * 2 + 1] + bpos[j], 0.0f);
  }
  f32x4 hvc[4];
#pragma unroll
  for (int it = 0; it < 4; ++it) {
    int p = tid + it * 512;
    int m = p >> 5, c4 = p & 31;
    hvc[it] = *(const f32x4*)(hvp + (size_t)(node0 + m) * 128 + c4 * 4);
  }
  __syncthreads();

  f32x4 acc[2] = {f32x4{0.f,0.f,0.f,0.f}, f32x4{0.f,0.f,0.f,0.f}};
  {
    const char* whb = (const char*)Wh2 + (wc * 16 + l15) * 64 + lk * 16;
#pragma unroll
    for (int ks = 0; ks < 16; ++ks) {
      s16x8 bf = *(const s16x8*)(whb + ks * 4096);
#pragma unroll
      for (int mi = 0; mi < 2; ++mi) {
        int m = wr * 32 + mi * 16 + l15;
        s16x8 af = *(const s16x8*)(lds + SWZA(m, ks * 64 + lk * 16));
        acc[mi] = __builtin_amdgcn_mfma_f32_16x16x32_bf16(af, bf, acc[mi], 0, 0, 0);
      }
    }
  }
  __syncthreads();

#pragma unroll
  for (int it = 0; it < 8; ++it) {
    int p = tid + it * 512;
    int m = p >> 6, j = p & 63;
    *(unsigned short*)(lds + SWZ2(m, j * 2)) = f2bf(ev[it]);
  }
#pragma unroll
  for (int it = 0; it < 4; ++it) {
    int p = tid + it * 512;
    int m = p >> 5, c4 = p & 31;
    *(unsigned long long*)(lds + SWZ2(m, 256 + c4 * 8)) = pack4bf(hvc[it]);
  }
  {
    float bb = bhid[wc * 16 + l15];
    int cb = (64 + wc * 16 + l15) * 2;
#pragma unroll
    for (int mi = 0; mi < 2; ++mi) {
#pragma unroll
      for (int r = 0; r < 4; ++r) {
        int m = wr * 32 + mi * 16 + lk * 4 + r;
        float av = fmaxf(acc[mi][r] + bb, 0.0f);
        *(unsigned short*)(lds + SWZ2(m, cb)) = f2bf(av);
      }
    }
  }
  __syncthreads();

  f32x4 acc2[4][4];
#pragma unroll
  for (int mi = 0; mi < 4; ++mi)
#pragma unroll
    for (int j = 0; j < 4; ++j) acc2[mi][j] = f32x4{0.f,0.f,0.f,0.f};
#pragma unroll
  for (int kk = 0; kk < 8; ++kk) {
    s16x8 a[4];
#pragma unroll
    for (int mi = 0; mi < 4; ++mi)
      a[mi] = *(const s16x8*)(lds + SWZ2(mi * 16 + l15, kk * 64 + lk * 16));
    const char* wb = (const char*)W2 + kk * 32768 + lk * 16;
#pragma unroll
    for (int j = 0; j < 4; ++j) {
      s16x8 bf = *(const s16x8*)(wb + (size_t)(16 * w + 128 * j + l15) * 64);
#pragma unroll
      for (int mi = 0; mi < 4; ++mi)
        acc2[mi][j] = __builtin_amdgcn_mfma_f32_16x16x32_bf16(a[mi], bf, acc2[mi][j], 0, 0, 0);
    }
  }
  float bs[4];
  const int d = 16 * w + l15;
#pragma unroll
  for (int j = 0; j < 4; ++j) bs[j] = biasg[128 * j + d];
  unsigned long long actmask = __ballot(tsm[node0 + l] == 1);
#pragma unroll
  for (int mi = 0; mi < 4; ++mi) {
#pragma unroll
    for (int r = 0; r < 4; ++r) {
      int m = mi * 16 + lk * 4 + r;
      size_t node = (size_t)node0 + m;
      int act = (int)((actmask >> m) & 1ull);
      float gi = acc2[mi][0][r] + bs[0];
      float gf = acc2[mi][1][r] + bs[1];
      float gg = acc2[mi][2][r] + bs[2];
      float go = acc2[mi][3][r] + bs[3];
      float i_ = fsig(gi), f_ = fsig(gf), o_ = fsig(go);
      float g_ = ftanh(gg);
      float co = cvp[node * 128 + d];
      float ho = hvp[node * 128 + d];
      float cn = f_ * co + i_ * g_;
      float hn = o_ * ftanh(cn);
      hvo[node * 128 + d] = act ? hn : ho;
      cvo[node * 128 + d] = act ? cn : co;
    }
  }
}

extern "C" void kernel_launch(void* const* d_in, const int* in_sizes, int n_in,
                              void* d_out, int out_size, void* d_ws, size_t ws_size,
                              hipStream_t stream) {
  const float* Hv   = (const float*)d_in[0];
  const float* hvv  = (const float*)d_in[1];
  const float* xv   = (const float*)d_in[2];
  const float* hvp  = (const float*)d_in[3];
  const float* cvp  = (const float*)d_in[4];
  const int*   tsm  = (const int*)d_in[5];
  const float* Wpos = (const float*)d_in[6];
  const float* bpos = (const float*)d_in[7];
  const float* Whid = (const float*)d_in[8];
  const float* bhid = (const float*)d_in[9];
  const float* Wih  = (const float*)d_in[10];
  const float* bih  = (const float*)d_in[11];
  const float* Whh  = (const float*)d_in[12];
  const float* bhh  = (const float*)d_in[13];

  unsigned short* wsWh2 = (unsigned short*)d_ws;   // 32768 bf16 (64KB)
  unsigned short* wsW2  = wsWh2 + 32768;           // 131072 bf16 (256KB)
  float* wsBias = (float*)(wsW2 + 131072);         // 512 f32

  const size_t av_off = 1 << 20;
  const size_t need = av_off + (size_t)N_NODES * 64 * 2;
  unsigned short* wsAv = (unsigned short*)((char*)d_ws + av_off);

  prep_kernel<<<512, 256, 0, stream>>>(Whid, Wih, Whh, bih, bhh,
                                       wsWh2, wsW2, wsBias);

  float* hvo = (float*)d_out;
  float* cvo = hvo + (size_t)N_NODES * 128;

  if (ws_size >= need) {
    node_av_kernel<<<N_NODES / 64, 256, 0, stream>>>(Hv, hvv, wsWh2, bhid, wsAv);
    node_gate_kernel<<<N_NODES / 64, 512, 0, stream>>>(
        xv, hvp, cvp, tsm, Wpos, bpos, wsAv, wsW2, wsBias, hvo, cvo);
  } else {
    node_rnn_fused<<<N_NODES / 64, 512, 0, stream>>>(
        Hv, hvv, xv, hvp, cvp, tsm, Wpos, bpos, bhid,
        wsWh2, wsW2, wsBias, hvo, cvo);
  }
}